// Round 6
// baseline (485.405 us; speedup 1.0000x reference)
//
#include <hip/hip_runtime.h>
#include <math.h>

// Problem constants (from reference setup_inputs)
#define L_SEQ 1024
#define BATCH 64
#define HDIM  1024
#define WPB   4      // waves per block (256 threads)

#define LOG2E 1.44269504088896340736f

// ---------------------------------------------------------------------------
// Fused flash-decode attention, single launch.
// Phase 1 (all blocks): one wave per (b, l-chunk) computes online-softmax
//   partials exactly as before (skinny body, ping-pong prefetch, wave-uniform
//   rescale, base-2 softmax). Lane j owns h = {4j, 256+4j, 512+4j, 768+4j}.
// Phase 2 (last block per b): blocks of a given b (SPLIT/WPB of them) bump a
//   device-scope counter after a release fence; the last arriver reduces all
//   SPLIT partial records for its b and writes context[b,:]. The reduce
//   overlaps with other batches' phase-1 blocks still streaming; records are
//   L2-hot. No spinning -> no co-residency assumption (XCD-safe, G16).
// Partial record r = b*SPLIT + k:
//   wsC[r*HDIM + h]      = sum_{l in chunk} 2^(s_l*log2e - m_r) * enc[l,b,h]
//   wsML[2r], wsML[2r+1] = (m_r, lsum_r)   (m in base-2 domain)
// ---------------------------------------------------------------------------
template <int SPLIT, int CHUNK>
__global__ __launch_bounds__(256) void attn_fused_kernel(
    const float* __restrict__ enc, const float* __restrict__ dec,
    float* __restrict__ wsC, float* __restrict__ wsML,
    unsigned int* __restrict__ cnt, float* __restrict__ out)
{
    constexpr int BPB = SPLIT / WPB;     // blocks per batch b (all 4 waves of a
                                         // block share one b since SPLIT%4==0)
    const int tid  = threadIdx.x;
    const int lane = tid & 63;
    const int wave = tid >> 6;
    const int w    = blockIdx.x * WPB + wave;   // global wave id
    const int b    = w / SPLIT;
    const int k    = w - b * SPLIT;
    const int l0   = k * CHUNK;

    // ---- Phase 1: partial over this wave's l-chunk ----
    const float4* decv = (const float4*)(dec + (size_t)b * HDIM);
    float4 d[4];
    #pragma unroll
    for (int q = 0; q < 4; ++q) d[q] = decv[lane + 64 * q];

    float m = -INFINITY;   // running max (base-2 domain)
    float lsum = 0.0f;
    float4 a[4];
    #pragma unroll
    for (int q = 0; q < 4; ++q) a[q] = make_float4(0.f, 0.f, 0.f, 0.f);

    const size_t row_stride = (size_t)BATCH * HDIM;
    const float* base0 = enc + ((size_t)l0 * BATCH + b) * HDIM;

    float4 B0[4], B1[4];
    auto process = [&](const float4* e) {
        float p = 0.0f;
        #pragma unroll
        for (int q = 0; q < 4; ++q) {
            p = fmaf(e[q].x, d[q].x, p);
            p = fmaf(e[q].y, d[q].y, p);
            p = fmaf(e[q].z, d[q].z, p);
            p = fmaf(e[q].w, d[q].w, p);
        }
        #pragma unroll
        for (int off = 32; off > 0; off >>= 1)
            p += __shfl_xor(p, off, 64);

        const float s = p * LOG2E;
        if (s > m) {                       // wave-uniform; rare after warmup
            const float scale = exp2f(m - s);   // 2^(-inf) = 0 on first row
            lsum *= scale;
            #pragma unroll
            for (int q = 0; q < 4; ++q) {
                a[q].x *= scale;  a[q].y *= scale;
                a[q].z *= scale;  a[q].w *= scale;
            }
            m = s;
        }
        const float wgt = exp2f(s - m);
        lsum += wgt;
        #pragma unroll
        for (int q = 0; q < 4; ++q) {
            a[q].x = fmaf(wgt, e[q].x, a[q].x);
            a[q].y = fmaf(wgt, e[q].y, a[q].y);
            a[q].z = fmaf(wgt, e[q].z, a[q].z);
            a[q].w = fmaf(wgt, e[q].w, a[q].w);
        }
    };

    {
        const float4* row = (const float4*)base0;
        #pragma unroll
        for (int q = 0; q < 4; ++q) B0[q] = row[lane + 64 * q];
    }
    #pragma unroll
    for (int g = 0; g < CHUNK; g += 2) {
        {
            const float4* row = (const float4*)(base0 + (size_t)(g + 1) * row_stride);
            #pragma unroll
            for (int q = 0; q < 4; ++q) B1[q] = row[lane + 64 * q];
        }
        process(B0);
        if (g + 2 < CHUNK) {
            const float4* row = (const float4*)(base0 + (size_t)(g + 2) * row_stride);
            #pragma unroll
            for (int q = 0; q < 4; ++q) B0[q] = row[lane + 64 * q];
        }
        process(B1);
    }

    const size_t r = (size_t)b * SPLIT + k;
    float4* C = (float4*)(wsC + r * (size_t)HDIM);
    #pragma unroll
    for (int q = 0; q < 4; ++q) C[lane + 64 * q] = a[q];
    if (lane == 0) {
        wsML[2 * r]     = m;
        wsML[2 * r + 1] = lsum;
    }

    // ---- Arrival: last block of this b does the combine ----
    __syncthreads();
    __shared__ unsigned int s_old;
    if (tid == 0) {
        __threadfence();                           // release partial writes
        s_old = atomicAdd(&cnt[b], 1u);            // device scope by default
    }
    __syncthreads();
    if (s_old != BPB - 1) return;

    // ---- Phase 2: reduce SPLIT records for b; thread t owns float4 #t ----
    __threadfence();                               // acquire others' writes

    const float* mlb = wsML + 2 * (size_t)b * SPLIT;
    float M = -INFINITY;
    #pragma unroll 8
    for (int kk = 0; kk < SPLIT; ++kk)
        M = fmaxf(M, mlb[2 * kk]);

    float Lt = 0.0f;
    float4 acc = make_float4(0.f, 0.f, 0.f, 0.f);
    const float4* Cb = (const float4*)(wsC + (size_t)b * SPLIT * HDIM);
    #pragma unroll 4
    for (int kk = 0; kk < SPLIT; ++kk) {
        const float wgt = exp2f(mlb[2 * kk] - M);
        Lt = fmaf(mlb[2 * kk + 1], wgt, Lt);
        const float4 c = Cb[(size_t)kk * (HDIM / 4) + tid];
        acc.x = fmaf(wgt, c.x, acc.x);
        acc.y = fmaf(wgt, c.y, acc.y);
        acc.z = fmaf(wgt, c.z, acc.z);
        acc.w = fmaf(wgt, c.w, acc.w);
    }
    const float inv = 1.0f / Lt;
    float4 o;
    o.x = acc.x * inv;  o.y = acc.y * inv;
    o.z = acc.z * inv;  o.w = acc.w * inv;
    ((float4*)(out + (size_t)b * HDIM))[tid] = o;
}

extern "C" void kernel_launch(void* const* d_in, const int* in_sizes, int n_in,
                              void* d_out, int out_size, void* d_ws, size_t ws_size,
                              hipStream_t stream) {
    const float* enc = (const float*)d_in[0];   // [L, B, H] fp32
    const float* dec = (const float*)d_in[1];   // [1, B, H] fp32
    float* out = (float*)d_out;                 // [B, H] fp32

    // ws layout: wsC [B*SPLIT*H] | wsML [B*SPLIT*2] | cnt [B] (uint)
    // ws_size is launch-invariant -> identical choice every call -> capture-safe.
    constexpr int SPLIT = 64, CHUNK = L_SEQ / SPLIT;
    const size_t need = (size_t)BATCH * SPLIT * HDIM * sizeof(float)
                      + (size_t)BATCH * SPLIT * 2 * sizeof(float)
                      + (size_t)BATCH * sizeof(unsigned int);

    float* wsC = (float*)d_ws;
    float* wsML = wsC + (size_t)BATCH * SPLIT * HDIM;
    unsigned int* cnt = (unsigned int*)(wsML + 2 * (size_t)BATCH * SPLIT);

    if (ws_size >= need) {
        // counters are poisoned to 0xAA each iteration -> re-zero (capture-safe)
        hipMemsetAsync(cnt, 0, BATCH * sizeof(unsigned int), stream);
        attn_fused_kernel<SPLIT, CHUNK>
            <<<(BATCH * SPLIT) / WPB, 256, 0, stream>>>(enc, dec, wsC, wsML, cnt, out);
    } else {
        // Tiny-ws fallback (unused in practice): SPLIT=8 variant
        constexpr int S2 = 8, C2 = L_SEQ / S2;
        float* wsML2 = wsC + (size_t)BATCH * S2 * HDIM;
        unsigned int* cnt2 = (unsigned int*)(wsML2 + 2 * (size_t)BATCH * S2);
        hipMemsetAsync(cnt2, 0, BATCH * sizeof(unsigned int), stream);
        attn_fused_kernel<S2, C2>
            <<<(BATCH * S2) / WPB, 256, 0, stream>>>(enc, dec, wsC, wsML2, cnt2, out);
    }
}